// Round 14
// baseline (208.904 us; speedup 1.0000x reference)
//
#include <hip/hip_runtime.h>
#include <hip/hip_bf16.h>

typedef __attribute__((ext_vector_type(8))) short short8;          // 8 bf16 (4 VGPRs) MFMA frag
typedef __attribute__((ext_vector_type(4))) short short4b;         // 4 bf16 (8 B)
typedef __attribute__((ext_vector_type(4))) float float4v;         // MFMA acc
typedef __attribute__((ext_vector_type(8))) unsigned short ushort8v;

#define DIM 1024
#define NHEADS 16
#define HDIM 64
#define BATCH 2
#define SEQ 2048
#define LOG2E 1.4426950408889634f

__device__ __forceinline__ unsigned short f2bf(float f) {
    unsigned int u = __float_as_uint(f);
    unsigned int r = (u + 0x7fffu + ((u >> 16) & 1u)) >> 16;
    return (unsigned short)r;
}

__device__ __forceinline__ unsigned int cvt_pk_bf16(float lo, float hi) {
    unsigned int r;
    asm("v_cvt_pk_bf16_f32 %0, %1, %2" : "=v"(r) : "v"(lo), "v"(hi));
    return r;
}

__device__ __forceinline__ void gload_lds16(const void* g, void* l) {
    __builtin_amdgcn_global_load_lds(
        (const __attribute__((address_space(1))) void*)g,
        (__attribute__((address_space(3))) void*)l,
        16, 0, 0);
}

typedef __attribute__((address_space(3))) const unsigned short* lds_us_cp;

// HW transpose read: per-lane addr p+lane*8B; lane(lg,lr) elem j gets the
// bf16 at byte (p_base + OFF) + lg*128 + j*32 + lr*2.
template<int OFF>
__device__ __forceinline__ short4b ds_tr16(const unsigned short* p) {
    short4b r;
    asm volatile("ds_read_b64_tr_b16 %0, %1 offset:%2"
                 : "=v"(r) : "v"((lds_us_cp)p), "i"(OFF));
    return r;
}

// ---------------------------------------------------------------- cast x -> bf16
__global__ __launch_bounds__(256) void cast_x_kernel(const float* __restrict__ x,
                                                     unsigned short* __restrict__ xb) {
    int i = (blockIdx.x * 256 + threadIdx.x) * 8;
    float4 a = *(const float4*)(x + i);
    float4 b = *(const float4*)(x + i + 4);
    ushort8v o;
    o[0] = f2bf(a.x); o[1] = f2bf(a.y); o[2] = f2bf(a.z); o[3] = f2bf(a.w);
    o[4] = f2bf(b.x); o[5] = f2bf(b.y); o[6] = f2bf(b.z); o[7] = f2bf(b.w);
    *(ushort8v*)(xb + i) = o;
}

// ------------------------------------------- transpose+cast weight [K][N] -> [N][K] bf16
__global__ __launch_bounds__(256) void tcast_kernel(const float* __restrict__ W,
                                                    unsigned short* __restrict__ Wt,
                                                    int K, int N) {
    __shared__ float tile[32][33];
    int tx = threadIdx.x & 31, ty = threadIdx.x >> 5;   // 32 cols x 8 rows
    int n0 = blockIdx.x * 32, k0 = blockIdx.y * 32;
#pragma unroll
    for (int i = 0; i < 4; ++i)
        tile[ty + i * 8][tx] = W[(size_t)(k0 + ty + i * 8) * N + n0 + tx];
    __syncthreads();
#pragma unroll
    for (int i = 0; i < 4; ++i)
        Wt[(size_t)(n0 + ty + i * 8) * K + k0 + tx] = f2bf(tile[tx][ty + i * 8]);
}

// ---------------------------------------------------------------- QKV GEMM
// 128x128 tile. Epilogue: C tile -> LDS (bf16, +bias, q*SCALE*log2e) ->
// coalesced ushort8 stores to the (B,H,N,D) scatter layout.
__global__ __launch_bounds__(256) void gemm_qkv_kernel(
    const unsigned short* __restrict__ A, const unsigned short* __restrict__ Bt,
    const float* __restrict__ bias,
    unsigned short* __restrict__ qb, unsigned short* __restrict__ kb,
    unsigned short* __restrict__ vb) {
    __shared__ unsigned short As[128 * 32];
    __shared__ unsigned short Bs[128 * 32];
    __shared__ unsigned short Cs[128 * 136];   // +8 shorts pad per row
    const int t = threadIdx.x;
    const int lane = t & 63;
    const int w = t >> 6;
    const int wr = w >> 1, wc = w & 1;
    const int lg = lane >> 4, lr = lane & 15;
    const int m0 = blockIdx.y * 128;
    const int n0 = blockIdx.x * 128;
    const int K = 1024;

    float4v acc[4][4] = {};

    for (int k0 = 0; k0 < K; k0 += 32) {
#pragma unroll
        for (int i = 0; i < 2; ++i) {
            int slot = i * 256 + t;            // 16-B units
            int row = slot >> 2;               // 64 B per row (32 bf16)
            int cb = (slot & 3) * 16;
            gload_lds16((const char*)(A + (size_t)(m0 + row) * K + k0) + cb,
                        (char*)As + slot * 16);
            gload_lds16((const char*)(Bt + (size_t)(n0 + row) * K + k0) + cb,
                        (char*)Bs + slot * 16);
        }
        __syncthreads();
        short8 af[4], bf[4];
#pragma unroll
        for (int m = 0; m < 4; ++m)
            af[m] = *(const short8*)(As + (wr * 64 + m * 16 + lr) * 32 + lg * 8);
#pragma unroll
        for (int n = 0; n < 4; ++n)
            bf[n] = *(const short8*)(Bs + (wc * 64 + n * 16 + lr) * 32 + lg * 8);
#pragma unroll
        for (int m = 0; m < 4; ++m)
#pragma unroll
            for (int n = 0; n < 4; ++n)
                acc[m][n] = __builtin_amdgcn_mfma_f32_16x16x32_bf16(af[m], bf[n], acc[m][n], 0, 0, 0);
        __syncthreads();
    }

    const int which = n0 >> 10;                  // block-uniform: 0=q 1=k 2=v
    unsigned short* dst = (which == 0) ? qb : ((which == 1) ? kb : vb);
    const float sc = (which == 0) ? 0.125f * LOG2E : 1.0f;

    // C tile -> LDS (row-major, padded)
#pragma unroll
    for (int n = 0; n < 4; ++n) {
        int col = wc * 64 + n * 16 + lr;
        float bv = bias[n0 + col];
#pragma unroll
        for (int m = 0; m < 4; ++m) {
#pragma unroll
            for (int r = 0; r < 4; ++r) {
                int row = wr * 64 + m * 16 + lg * 4 + r;
                Cs[row * 136 + col] = f2bf((acc[m][n][r] + bv) * sc);
            }
        }
    }
    __syncthreads();

    // LDS -> global: 256 segments (128 rows x 2 heads) of 128 B; 8 lanes/segment.
    const int colh0 = n0 & 1023;
#pragma unroll
    for (int it = 0; it < 8; ++it) {
        int seg = it * 32 + (t >> 3);            // 0..255
        int row = seg >> 1, hh = seg & 1, chunk = t & 7;
        int grow = m0 + row;                     // 0..4095
        int b = grow >> 11, nn = grow & 2047;
        int colh = colh0 + hh * 64;              // within this matrix
        int h = colh >> 6;
        int d = chunk * 8;
        ushort8v vv = *(const ushort8v*)(Cs + row * 136 + hh * 64 + d);
        *(ushort8v*)(&dst[((size_t)(b * NHEADS + h) * SEQ + nn) * HDIM + d]) = vv;
    }
}

// ---------------------------------------------------------------- flash attention + rCM skip
// Grid: (N/64, B*H). 4 waves x 16 q-rows. KV tiles of 64, TRIPLE-buffered,
// staged 2 tiles ahead via global_load_lds; counted s_waitcnt vmcnt(4) +
// raw s_barrier per tile (T4: never drain vmcnt to 0 in the main loop).
// Stage issue is AFTER the barrier so no wave overwrites a buffer another
// wave is still computing on. Tail: vmcnt(0) on the last iteration.
// K: row-major [kv][64] with XOR swizzle byte^((kv&7)<<4), pre-swizzled source.
// V: subtiled [d/16][kv/4][4][16] (tr_b16-ready), source-permuted linear dest.
// Swapped QK^T; no online max (q pre-scaled by log2e); l via ones-MFMA.
__global__ __launch_bounds__(256) void attn_kernel(
    const unsigned short* __restrict__ q, const unsigned short* __restrict__ k,
    const unsigned short* __restrict__ v, const float* __restrict__ x,
    const float* __restrict__ tptr, unsigned short* __restrict__ y) {
    __shared__ unsigned short Ks[3][64 * 64];
    __shared__ unsigned short Vt[3][64 * 64];
    const int t = threadIdx.x;
    const int lane = t & 63;
    const int w = t >> 6;
    const int lg = lane >> 4, lr = lane & 15;
    const int bh = blockIdx.y;
    const int b = bh >> 4, h = bh & 15;
    const int q0 = blockIdx.x * 64 + w * 16;
    const size_t head_off = (size_t)bh * SEQ * HDIM;
    const unsigned short* qh = q + head_off;
    const unsigned short* kh = k + head_off;
    const unsigned short* vh = v + head_off;
    const int NT = SEQ / 64;

    short8 qf[2];
#pragma unroll
    for (int ks = 0; ks < 2; ++ks)
        qf[ks] = *(const short8*)(qh + (size_t)(q0 + lr) * HDIM + ks * 32 + lg * 8);

    union { unsigned short u[8]; short8 s8; } ones;
#pragma unroll
    for (int j = 0; j < 8; ++j) ones.u[j] = 0x3F80;   // bf16 1.0

    float4v acc[4] = {};
    float4v acc_l = {};

    // ---- staging (K: XOR-swizzled source; V: subtile-permuted source)
    auto stage = [&](int tile, unsigned short* kd, unsigned short* vd) {
        const char* ktile = (const char*)(kh + (size_t)tile * 64 * HDIM);
#pragma unroll
        for (int i = 0; i < 2; ++i) {
            int slot = (i * 256 + t) * 16;
            int row = slot >> 7;
            int src = slot ^ ((row & 7) << 4);
            gload_lds16(ktile + src, (char*)kd + slot);
        }
        const unsigned short* vt0 = vh + (size_t)tile * 64 * HDIM;
#pragma unroll
        for (int i = 0; i < 2; ++i) {
            int s = i * 256 + t;                // 16-B slot
            int st = s >> 3, g = s & 7;         // subtile, granule
            int db = st >> 4, kvg = st & 15;
            int kv = kvg * 4 + (g >> 1);
            int d = db * 16 + (g & 1) * 8;
            gload_lds16((const char*)(vt0 + (size_t)kv * HDIM + d),
                        (char*)vd + s * 16);
        }
    };

    unsigned short *ksA = Ks[0], *ksB = Ks[1], *ksC = Ks[2];
    unsigned short *vtA = Vt[0], *vtB = Vt[1], *vtC = Vt[2];

    stage(0, ksA, vtA);           // 4 vmem ops
    stage(1, ksB, vtB);           // 8 in flight

    for (int tt = 0; tt < NT; ++tt) {
        // ---- wait for tile tt (oldest 4 loads), keep tile tt+1 in flight
        if (tt == NT - 1) { asm volatile("s_waitcnt vmcnt(0)" ::: "memory"); }
        else              { asm volatile("s_waitcnt vmcnt(4)" ::: "memory"); }
        __builtin_amdgcn_s_barrier();

        // ---- issue tile tt+2 into the buffer freed at iteration tt-1
        if (tt + 2 < NT) stage(tt + 2, ksC, vtC);

        // ---- S^T = K Q^T : lane holds S[q=lr][k = n*16 + lg*4 + r]
        float4v s[4];
        __builtin_amdgcn_s_setprio(1);
#pragma unroll
        for (int n = 0; n < 4; ++n) {
            s[n] = (float4v){0.f, 0.f, 0.f, 0.f};
#pragma unroll
            for (int ks = 0; ks < 2; ++ks) {
                int row = n * 16 + lr;
                int byte = (row * 128 + (ks * 32 + lg * 8) * 2) ^ ((row & 7) << 4);
                short8 kf = *(const short8*)((const char*)ksA + byte);
                s[n] = __builtin_amdgcn_mfma_f32_16x16x32_bf16(kf, qf[ks], s[n], 0, 0, 0);
            }
        }
        __builtin_amdgcn_s_setprio(0);

        // ---- p = exp2(s) (scores arrive in log2 domain; no max, no rescale)
#pragma unroll
        for (int n = 0; n < 4; ++n)
#pragma unroll
            for (int r = 0; r < 4; ++r)
                s[n][r] = exp2f(s[n][r]);

        // ---- PV: P packed in-register; V via HW transpose reads.
        const unsigned short* vbase = vtA + (size_t)lane * 4;   // lane*8 bytes
#pragma unroll
        for (int ks = 0; ks < 2; ++ks) {
            union { unsigned int u[4]; short8 s8; } pu;
            pu.u[0] = cvt_pk_bf16(s[2 * ks][0], s[2 * ks][1]);
            pu.u[1] = cvt_pk_bf16(s[2 * ks][2], s[2 * ks][3]);
            pu.u[2] = cvt_pk_bf16(s[2 * ks + 1][0], s[2 * ks + 1][1]);
            pu.u[3] = cvt_pk_bf16(s[2 * ks + 1][2], s[2 * ks + 1][3]);

            short4b lo0, hi0, lo1, hi1, lo2, hi2, lo3, hi3;
            if (ks == 0) {
                lo0 = ds_tr16<0>(vbase);    hi0 = ds_tr16<512>(vbase);
                lo1 = ds_tr16<2048>(vbase); hi1 = ds_tr16<2560>(vbase);
                lo2 = ds_tr16<4096>(vbase); hi2 = ds_tr16<4608>(vbase);
                lo3 = ds_tr16<6144>(vbase); hi3 = ds_tr16<6656>(vbase);
            } else {
                lo0 = ds_tr16<1024>(vbase); hi0 = ds_tr16<1536>(vbase);
                lo1 = ds_tr16<3072>(vbase); hi1 = ds_tr16<3584>(vbase);
                lo2 = ds_tr16<5120>(vbase); hi2 = ds_tr16<5632>(vbase);
                lo3 = ds_tr16<7168>(vbase); hi3 = ds_tr16<7680>(vbase);
            }
            asm volatile("s_waitcnt lgkmcnt(0)" ::: "memory");
            __builtin_amdgcn_sched_barrier(0);

            __builtin_amdgcn_s_setprio(1);
            acc[0] = __builtin_amdgcn_mfma_f32_16x16x32_bf16(
                pu.s8, __builtin_shufflevector(lo0, hi0, 0, 1, 2, 3, 4, 5, 6, 7), acc[0], 0, 0, 0);
            acc[1] = __builtin_amdgcn_mfma_f32_16x16x32_bf16(
                pu.s8, __builtin_shufflevector(lo1, hi1, 0, 1, 2, 3, 4, 5, 6, 7), acc[1], 0, 0, 0);
            acc[2] = __builtin_amdgcn_mfma_f32_16x16x32_bf16(
                pu.s8, __builtin_shufflevector(lo2, hi2, 0, 1, 2, 3, 4, 5, 6, 7), acc[2], 0, 0, 0);
            acc[3] = __builtin_amdgcn_mfma_f32_16x16x32_bf16(
                pu.s8, __builtin_shufflevector(lo3, hi3, 0, 1, 2, 3, 4, 5, 6, 7), acc[3], 0, 0, 0);
            acc_l = __builtin_amdgcn_mfma_f32_16x16x32_bf16(
                pu.s8, ones.s8, acc_l, 0, 0, 0);
            __builtin_amdgcn_s_setprio(0);
        }

        // ---- rotate buffers (tile tt's buffer becomes the stage target
        //      two iterations from now; freed for writing at tt+1's barrier)
        unsigned short* tk = ksA; ksA = ksB; ksB = ksC; ksC = tk;
        unsigned short* tv = vtA; vtA = vtB; vtB = vtC; vtC = tv;
    }

    // ---- rCM skip epilogue -> y bf16 (B,N,C); acc_l[r] = l for row lg*4+r
    float tv2 = *tptr;
    float c_skip = 1.0f / (tv2 * tv2 + 1.0f);
    float c_out = tv2 * rsqrtf(1.0f + tv2 * tv2);
#pragma unroll
    for (int vn = 0; vn < 4; ++vn) {
#pragma unroll
        for (int r = 0; r < 4; ++r) {
            int n = blockIdx.x * 64 + w * 16 + lg * 4 + r;
            int c = h * 64 + vn * 16 + lr;
            size_t off = (size_t)(b * SEQ + n) * DIM + c;
            float av = acc[vn][r] / acc_l[r];
            float o = c_skip * x[off] + c_out * av;
            y[off] = f2bf(o);
        }
    }
}

// ---------------------------------------------------------------- out projection
// 64x64 tile, BK=32, 4 waves (2x2 of 32x32): grid 16x64 = 1024 blocks = 4/CU.
__global__ __launch_bounds__(256) void gemm_proj_kernel(
    const unsigned short* __restrict__ A, const unsigned short* __restrict__ Bt,
    const float* __restrict__ bias, float* __restrict__ out) {
    __shared__ unsigned short As[64 * 32];
    __shared__ unsigned short Bs[64 * 32];
    const int t = threadIdx.x;
    const int lane = t & 63;
    const int w = t >> 6;
    const int wr = w >> 1, wc = w & 1;
    const int lg = lane >> 4, lr = lane & 15;
    const int m0 = blockIdx.y * 64;
    const int n0 = blockIdx.x * 64;
    const int K = 1024;

    float4v acc[2][2] = {};

    for (int k0 = 0; k0 < K; k0 += 32) {
        {
            int slot = t;                      // 16-B units, 256 slots = 4 KB
            int row = slot >> 2;               // 64 B per row (32 bf16)
            int cb = (slot & 3) * 16;
            gload_lds16((const char*)(A + (size_t)(m0 + row) * K + k0) + cb,
                        (char*)As + slot * 16);
            gload_lds16((const char*)(Bt + (size_t)(n0 + row) * K + k0) + cb,
                        (char*)Bs + slot * 16);
        }
        __syncthreads();
        short8 af[2], bf[2];
#pragma unroll
        for (int m = 0; m < 2; ++m)
            af[m] = *(const short8*)(As + (wr * 32 + m * 16 + lr) * 32 + lg * 8);
#pragma unroll
        for (int n = 0; n < 2; ++n)
            bf[n] = *(const short8*)(Bs + (wc * 32 + n * 16 + lr) * 32 + lg * 8);
#pragma unroll
        for (int m = 0; m < 2; ++m)
#pragma unroll
            for (int n = 0; n < 2; ++n)
                acc[m][n] = __builtin_amdgcn_mfma_f32_16x16x32_bf16(af[m], bf[n], acc[m][n], 0, 0, 0);
        __syncthreads();
    }

#pragma unroll
    for (int n = 0; n < 2; ++n) {
        int col = n0 + wc * 32 + n * 16 + lr;
        float bv = bias[col];
#pragma unroll
        for (int m = 0; m < 2; ++m) {
#pragma unroll
            for (int r = 0; r < 4; ++r) {
                int row = m0 + wr * 32 + m * 16 + lg * 4 + r;
                out[(size_t)row * DIM + col] = acc[m][n][r] + bv;
            }
        }
    }
}

extern "C" void kernel_launch(void* const* d_in, const int* in_sizes, int n_in,
                              void* d_out, int out_size, void* d_ws, size_t ws_size,
                              hipStream_t stream) {
    const float* x      = (const float*)d_in[0];
    const float* tsc    = (const float*)d_in[1];
    const float* w_qkv  = (const float*)d_in[2];
    const float* b_qkv  = (const float*)d_in[3];
    const float* w_proj = (const float*)d_in[4];
    const float* b_proj = (const float*)d_in[5];
    float* out = (float*)d_out;

    char* ws = (char*)d_ws;
    unsigned short* xb     = (unsigned short*)(ws);                 //  8 MiB
    unsigned short* wqkvT  = (unsigned short*)(ws + 8388608);       //  6 MiB
    unsigned short* wprojT = (unsigned short*)(ws + 14680064);      //  2 MiB
    unsigned short* qb     = (unsigned short*)(ws + 16777216);      //  8 MiB
    unsigned short* kb     = (unsigned short*)(ws + 25165824);      //  8 MiB
    unsigned short* vb     = (unsigned short*)(ws + 33554432);      //  8 MiB
    unsigned short* yb     = (unsigned short*)(ws + 41943040);      //  8 MiB (48 MiB total)

    cast_x_kernel<<<2048, 256, 0, stream>>>(x, xb);
    tcast_kernel<<<dim3(96, 32), 256, 0, stream>>>(w_qkv, wqkvT, 1024, 3072);
    tcast_kernel<<<dim3(32, 32), 256, 0, stream>>>(w_proj, wprojT, 1024, 1024);
    gemm_qkv_kernel<<<dim3(24, 32), 256, 0, stream>>>(xb, wqkvT, b_qkv, qb, kb, vb);
    attn_kernel<<<dim3(32, 32), 256, 0, stream>>>(qb, kb, vb, x, tsc, yb);
    gemm_proj_kernel<<<dim3(16, 64), 256, 0, stream>>>(yb, wprojT, b_proj, out);
}